// Round 11
// baseline (373.784 us; speedup 1.0000x reference)
//
#include <hip/hip_runtime.h>

#define NDIM 256
#define INNER 512
#define NH 8
#define ND 64
#define NS 32
#define NB 8
#define NP 30208   // padded node count (472*64, multiple of 512-window too)

typedef __attribute__((ext_vector_type(8))) short short8;   // 8 bf16 = 4 VGPR
typedef __attribute__((ext_vector_type(4))) float f32x4;

static __device__ __forceinline__ short f2bf(float f) {
  unsigned u = __float_as_uint(f);
  unsigned r = (u + 0x7fffu + ((u >> 16) & 1u)) >> 16;
  return (short)r;
}
static __device__ __forceinline__ float bf2f(short s) {
  return __uint_as_float(((unsigned)(unsigned short)s) << 16);
}

// async global->LDS, 16 B per lane; dest = uniform lds base + lane*16
static __device__ __forceinline__ void gl_lds16(const void* g, void* l) {
  __builtin_amdgcn_global_load_lds(
      (const __attribute__((address_space(1))) unsigned int*)g,
      (__attribute__((address_space(3))) unsigned int*)l, 16, 0, 0);
}

// ---------------------------------------------------------------------------
// k_pre:
//  blocks [0,769):    Bt1 [768][256] bf16 hi/lo (rows 0..511 Wfx^T,
//                     rows 512..767 (Wx@Wsl fused)^T) + bcomb
//  blocks [769,887):  seg boundaries (seg pre-memset 0x7f)
//  blocks [887,2775): xT: x[N,256] fp32 -> XTh/XTl [256][NP] bf16 hi/lo
//                     (64x64 LDS-transpose tiles; n >= N zero-filled)
// ---------------------------------------------------------------------------
__global__ __launch_bounds__(256) void k_pre(
    const float* __restrict__ x,
    const float* __restrict__ Wfx, const float* __restrict__ Wx,
    const float* __restrict__ bx, const float* __restrict__ Wsl,
    const float* __restrict__ bsl,
    short* __restrict__ Bt1h, short* __restrict__ Bt1l,
    float* __restrict__ bcomb,
    const int* __restrict__ batch, int* __restrict__ seg,
    short* __restrict__ XTh, short* __restrict__ XTl, int N)
{
  const int bid = blockIdx.x;
  const int tid = threadIdx.x;
  if (bid < 769) {                     // ---- weight prep
    int id = bid * 256 + tid;
    if (id < 131072) {
      int k = id >> 9, n = id & 511;
      float v = Wfx[k * 512 + n];
      short hi = f2bf(v); short lo = f2bf(v - bf2f(hi));
      Bt1h[n * 256 + k] = hi; Bt1l[n * 256 + k] = lo;
    } else if (id < 196608) {
      int e = id - 131072;
      int c = e & 255, k = e >> 8;
      int h = c >> 5, s = c & 31;
      float acc = 0.f;
      #pragma unroll 8
      for (int d = 0; d < 64; d++) acc += Wx[k * 512 + h * 64 + d] * Wsl[d * 32 + s];
      short hi = f2bf(acc); short lo = f2bf(acc - bf2f(hi));
      Bt1h[(512 + c) * 256 + k] = hi; Bt1l[(512 + c) * 256 + k] = lo;
    } else if (id < 196864) {
      int c = id - 196608;
      int h = c >> 5, s = c & 31;
      float acc = bsl[s];
      #pragma unroll 8
      for (int d = 0; d < 64; d++) acc += bx[h * 64 + d] * Wsl[d * 32 + s];
      bcomb[c] = acc;
    }
  } else if (bid < 887) {              // ---- segs
    int i = (bid - 769) * 256 + tid;
    if (i >= N) return;
    int b = batch[i];
    int p = (i == 0) ? -1 : batch[i - 1];
    if (i == 0) seg[0] = 0;
    for (int v = p + 1; v <= b; v++)
      if (v >= 1) atomicMin(&seg[v], i);
    if (i == N - 1)
      for (int v = b + 1; v <= 8; v++) atomicMin(&seg[v], N);
  } else {                             // ---- xT transpose-split
    __shared__ float xt[64][68];
    int tb = bid - 887;
    int ntile2 = tb >> 2;              // 0..471
    int dtile2 = tb & 3;               // 0..3
    int n0 = ntile2 * 64, d0 = dtile2 * 64;
    #pragma unroll
    for (int t = 0; t < 4; t++) {
      int idx2 = tid + t * 256;        // 1024 float4 chunks
      int row = idx2 >> 4, c4 = (idx2 & 15) * 4;
      float4 v = make_float4(0.f, 0.f, 0.f, 0.f);
      if (n0 + row < N) v = *(const float4*)&x[(size_t)(n0 + row) * 256 + d0 + c4];
      *(float4*)&xt[row][c4] = v;
    }
    __syncthreads();
    #pragma unroll
    for (int t = 0; t < 4; t++) {
      int idx2 = tid + t * 256;
      int drow = idx2 >> 4, nc4 = (idx2 & 15) * 4;
      short4 hv, lv;
      #pragma unroll
      for (int k = 0; k < 4; k++) {
        float v = xt[nc4 + k][drow];
        short hh = f2bf(v);
        ((short*)&hv)[k] = hh;
        ((short*)&lv)[k] = f2bf(v - bf2f(hh));
      }
      size_t dst = (size_t)(d0 + drow) * NP + n0 + nc4;
      *(short4*)&XTh[dst] = hv;
      *(short4*)&XTl[dst] = lv;
    }
  }
}

// ---------------------------------------------------------------------------
// k_w: logits[N,256] = x @ Wcomb (Bt1 rows 512..767), split-3 bf16 MFMA,
// tempered softmax -> w. Emits: w row-major hi/lo [n][256] (for k_outw),
// wT hi/lo [256][NP] (for k_G), snorm[b*256+hs] (register-exact atomics).
// 256 thr = 4 waves, BM=128 x BN=64, BK=32, 4 ct tiles.
// ---------------------------------------------------------------------------
__global__ __launch_bounds__(256) void k_w(
    const float* __restrict__ x,
    const short* __restrict__ Bt1h, const short* __restrict__ Bt1l,
    const float* __restrict__ bcomb, const float* __restrict__ gtemp,
    const int* __restrict__ batch,
    short* __restrict__ wh_out, short* __restrict__ wl_out,
    short* __restrict__ wTh, short* __restrict__ wTl,
    float* __restrict__ snorm, int N, int ntiles)
{
  __shared__ __align__(16) short smem[12288];   // 24.6 KB
  short* AhL = &smem[0];          // 4096 shorts (128x32)
  short* AlL = &smem[4096];
  short* BhL = &smem[8192];       // 2048 shorts (64x32)
  short* BlL = &smem[10240];
  __shared__ int b_sh[128];

  const int lid = blockIdx.x;
  const int xcd = lid & 7;
  const int idx = lid >> 3;
  const int ct  = idx & 3;
  const int rowt = xcd + 8 * (idx >> 2);
  if (rowt >= ntiles) return;
  const int row0 = rowt * 128;
  const int tid = threadIdx.x;
  const int lane = tid & 63, l15 = lane & 15, quad = lane >> 4;
  const int wvi = tid >> 6;
  const int wm = wvi & 1, wn = wvi >> 1;
  const int cb = 512 + ct * 64;        // Bt1 row base (Wcomb region)
  const int srow = lane & 15, schunk = lane >> 4;

  if (tid < 128) b_sh[tid] = (row0 + tid < N) ? batch[row0 + tid] : -1;

  f32x4 acc[4][2];
  #pragma unroll
  for (int i = 0; i < 4; i++)
    #pragma unroll
    for (int j = 0; j < 2; j++) acc[i][j] = (f32x4){0.f, 0.f, 0.f, 0.f};

  for (int kt = 0; kt < 8; kt++) {       // K=256, BK=32
    #pragma unroll
    for (int t = 0; t < 2; t++) {        // A: fp32 -> bf16 hi/lo in-register
      int idx2 = tid + t * 256;
      int row = idx2 >> 2, kc = (idx2 & 3) * 8;
      int gr = row0 + row; if (gr > N - 1) gr = N - 1;
      const float* xp = &x[(size_t)gr * 256 + kt * 32 + kc];
      float4 v1 = *(const float4*)xp;
      float4 v2 = *(const float4*)(xp + 4);
      float fv[8] = {v1.x, v1.y, v1.z, v1.w, v2.x, v2.y, v2.z, v2.w};
      short8 hv, lv;
      #pragma unroll
      for (int j = 0; j < 8; j++) {
        short hh = f2bf(fv[j]);
        hv[j] = hh; lv[j] = f2bf(fv[j] - bf2f(hh));
      }
      int dst = (row >> 4) * 512 + (kc >> 3) * 128 + (row & 15) * 8;
      *(short8*)&AhL[dst] = hv;
      *(short8*)&AlL[dst] = lv;
    }
    {                                     // B: DMA (64 rows x 32 k)
      int g2 = wvi;
      int br = cb + g2 * 16 + srow;
      size_t boff = (size_t)br * 256 + kt * 32 + schunk * 8;
      gl_lds16(Bt1h + boff, BhL + g2 * 512);
      gl_lds16(Bt1l + boff, BlL + g2 * 512);
    }
    __syncthreads();

    short8 ah[4], al[4];
    #pragma unroll
    for (int mt = 0; mt < 4; mt++) {
      int rg = wm * 4 + mt;
      ah[mt] = *(const short8*)&AhL[rg * 512 + quad * 128 + l15 * 8];
      al[mt] = *(const short8*)&AlL[rg * 512 + quad * 128 + l15 * 8];
    }
    #pragma unroll
    for (int nt = 0; nt < 2; nt++) {
      int rg = wn * 2 + nt;
      short8 bh = *(const short8*)&BhL[rg * 512 + quad * 128 + l15 * 8];
      short8 bl = *(const short8*)&BlL[rg * 512 + quad * 128 + l15 * 8];
      #pragma unroll
      for (int mt = 0; mt < 4; mt++) {
        acc[mt][nt] = __builtin_amdgcn_mfma_f32_16x16x32_bf16(ah[mt], bh, acc[mt][nt], 0, 0, 0);
        acc[mt][nt] = __builtin_amdgcn_mfma_f32_16x16x32_bf16(ah[mt], bl, acc[mt][nt], 0, 0, 0);
        acc[mt][nt] = __builtin_amdgcn_mfma_f32_16x16x32_bf16(al[mt], bh, acc[mt][nt], 0, 0, 0);
      }
    }
    __syncthreads();
  }

  // ---- softmax -> w values (saved in registers), row-major stores
  float w0a[4][4], w1a[4][4];
  const int lcb = ct * 64 + wn * 32;     // global hs col base, 32-aligned
  const int hsl0 = wn * 32 + l15;        // local col (0..63)
  const int hsl1 = wn * 32 + 16 + l15;
  {
    int hgrp = lcb >> 5;
    float inv_t = 1.0f / gtemp[hgrp];
    int lc0 = lcb + l15, lc1 = lcb + 16 + l15;
    float b0 = bcomb[lc0], b1 = bcomb[lc1];
    #pragma unroll
    for (int mt = 0; mt < 4; mt++) {
      #pragma unroll
      for (int r = 0; r < 4; r++) {
        float s0 = (acc[mt][0][r] + b0) * inv_t;
        float s1 = (acc[mt][1][r] + b1) * inv_t;
        float m = fmaxf(s0, s1);
        #pragma unroll
        for (int off = 1; off < 16; off <<= 1) m = fmaxf(m, __shfl_xor(m, off, 16));
        float e0 = __expf(s0 - m), e1 = __expf(s1 - m);
        float sum = e0 + e1;
        #pragma unroll
        for (int off = 1; off < 16; off <<= 1) sum += __shfl_xor(sum, off, 16);
        float inv = 1.0f / sum;
        float w0v = e0 * inv, w1v = e1 * inv;
        w0a[mt][r] = w0v; w1a[mt][r] = w1v;
        int row = row0 + wm * 64 + mt * 16 + quad * 4 + r;
        if (row < N) {
          size_t base = (size_t)row * 256;
          short h0 = f2bf(w0v), h1 = f2bf(w1v);
          wh_out[base + lc0] = h0; wl_out[base + lc0] = f2bf(w0v - bf2f(h0));
          wh_out[base + lc1] = h1; wl_out[base + lc1] = f2bf(w1v - bf2f(h1));
        }
      }
    }
  }

  // ---- snorm: per-graph column sums via LDS atomics, then global atomics
  {
    float* ln = (float*)smem;            // 512 floats [8 graphs][64 cols]
    __syncthreads();
    ln[tid] = 0.f; ln[tid + 256] = 0.f;
    __syncthreads();
    #pragma unroll
    for (int mt = 0; mt < 4; mt++)
      #pragma unroll
      for (int r = 0; r < 4; r++) {
        int rl = wm * 64 + mt * 16 + quad * 4 + r;
        if (row0 + rl < N) {
          int g = b_sh[rl];
          atomicAdd(&ln[g * 64 + hsl0], w0a[mt][r]);
          atomicAdd(&ln[g * 64 + hsl1], w1a[mt][r]);
        }
      }
    __syncthreads();
    #pragma unroll
    for (int k = 0; k < 2; k++) {
      int i = tid + k * 256;
      float v = ln[i];
      if (v != 0.f) atomicAdd(&snorm[(size_t)(i >> 6) * 256 + ct * 64 + (i & 63)], v);
    }
  }

  // ---- wT: LDS transpose (64 cols x 128 rows), store hi (pass0) / lo (pass1)
  {
    short (*T)[136] = (short(*)[136])&smem[0];   // 64 x 136 shorts
    #pragma unroll
    for (int pass = 0; pass < 2; pass++) {
      __syncthreads();
      #pragma unroll
      for (int mt = 0; mt < 4; mt++) {
        int rl = wm * 64 + mt * 16 + quad * 4;
        short4 sv0, sv1;
        #pragma unroll
        for (int r = 0; r < 4; r++) {
          bool ok = (row0 + rl + r) < N;
          float v0 = ok ? w0a[mt][r] : 0.f;
          float v1 = ok ? w1a[mt][r] : 0.f;
          short h0 = f2bf(v0);
          short h1 = f2bf(v1);
          ((short*)&sv0)[r] = pass ? f2bf(v0 - bf2f(h0)) : h0;
          ((short*)&sv1)[r] = pass ? f2bf(v1 - bf2f(h1)) : h1;
        }
        *(short4*)&T[hsl0][rl] = sv0;
        *(short4*)&T[hsl1][rl] = sv1;
      }
      __syncthreads();
      short* dst = pass ? wTl : wTh;
      #pragma unroll
      for (int t = 0; t < 4; t++) {
        int idx2 = tid + t * 256;                 // 1024 int4 chunks
        int row = idx2 >> 4, kc = (idx2 & 15) * 8;
        *(int4*)&dst[(size_t)(ct * 64 + row) * NP + row0 + kc] = *(const int4*)&T[row][kc];
      }
    }
  }
}

// ---------------------------------------------------------------------------
// k_G: G[b][hs][dim] = sum_{n in b} wT[hs][n] * xT[dim][n], split-3 MFMA over
// K=nodes. Grid (16 = 4 hs-tiles x 4 dim-tiles, 59 n-windows). Per-segment
// masking folded into boundary-chunk staging (wT only); fp32 atomic flush.
// ---------------------------------------------------------------------------
__global__ __launch_bounds__(256) void k_G(
    const short* __restrict__ wTh, const short* __restrict__ wTl,
    const short* __restrict__ XTh, const short* __restrict__ XTl,
    const int* __restrict__ seg, float* __restrict__ G, int N)
{
  __shared__ __align__(16) short smem[32768];   // 64 KB
  short* WhL = &smem[0];         // 8192 shorts (64 hs x 128 n)
  short* WlL = &smem[8192];
  short* XhL = &smem[16384];     // 8192 shorts (64 dim x 128 n)
  short* XlL = &smem[24576];

  const int tile = blockIdx.x;         // 0..15
  const int hstile = tile & 3, dtile = tile >> 2;
  const int hs0 = hstile * 64, d0 = dtile * 64;
  const int n0 = blockIdx.y * 512;
  const int tid = threadIdx.x;
  const int lane = tid & 63, l15 = lane & 15, quad = lane >> 4;
  const int wvi = tid >> 6;
  const int wm = wvi & 1, wn2 = wvi >> 1;
  const int srow = lane & 15, schunk = lane >> 4;
  const int nend = min(n0 + 512, N);

  f32x4 acc[2][2];
  #pragma unroll
  for (int i = 0; i < 2; i++)
    #pragma unroll
    for (int j = 0; j < 2; j++) acc[i][j] = (f32x4){0.f, 0.f, 0.f, 0.f};

  for (int b = 0; b < NB; b++) {
    int lo = max(seg[b], n0), hi = min(seg[b + 1], nend);
    if (lo >= hi) continue;
    int c0lo = (lo - n0) & ~127;
    int c0hi = hi - n0;
    for (int c0 = c0lo; c0 < c0hi; c0 += 128) {
      __syncthreads();
      bool full = (n0 + c0 >= lo) && (n0 + c0 + 128 <= hi);
      if (full) {                        // wT: DMA
        int g = wvi;
        #pragma unroll
        for (int u = 0; u < 4; u++) {
          size_t wo = (size_t)(hs0 + g * 16 + srow) * NP + n0 + c0 + u * 32 + schunk * 8;
          gl_lds16(wTh + wo, WhL + g * 2048 + u * 512);
          gl_lds16(wTl + wo, WlL + g * 2048 + u * 512);
        }
      } else {                           // wT: masked VGPR path (boundary)
        #pragma unroll
        for (int t = 0; t < 4; t++) {
          int idx2 = tid + t * 256;
          int row = idx2 >> 4, nc = (idx2 & 15) * 8;
          size_t src = (size_t)(hs0 + row) * NP + n0 + c0 + nc;
          short8 vh = *(const short8*)&wTh[src];
          short8 vl = *(const short8*)&wTl[src];
          #pragma unroll
          for (int j = 0; j < 8; j++) {
            int n = n0 + c0 + nc + j;
            if (n < lo || n >= hi) { vh[j] = 0; vl[j] = 0; }
          }
          int dst = (row >> 4) * 2048 + (nc >> 3) * 128 + (row & 15) * 8;
          *(short8*)&WhL[dst] = vh;
          *(short8*)&WlL[dst] = vl;
        }
      }
      {                                  // xT: DMA always (masked by wT zeros)
        int g = wvi;
        #pragma unroll
        for (int u = 0; u < 4; u++) {
          size_t xo = (size_t)(d0 + g * 16 + srow) * NP + n0 + c0 + u * 32 + schunk * 8;
          gl_lds16(XTh + xo, XhL + g * 2048 + u * 512);
          gl_lds16(XTl + xo, XlL + g * 2048 + u * 512);
        }
      }
      __syncthreads();

      #pragma unroll
      for (int k0 = 0; k0 < 128; k0 += 32) {
        int gbase = n0 + c0 + k0;
        if (gbase + 32 <= lo || gbase >= hi) continue;
        short8 ah[2], al[2], bh2[2], bl2[2];
        #pragma unroll
        for (int mt = 0; mt < 2; mt++) {
          int rr = wm * 32 + mt * 16 + l15;
          int off = (rr >> 4) * 2048 + ((k0 >> 3) + quad) * 128 + (rr & 15) * 8;
          ah[mt] = *(const short8*)&WhL[off];
          al[mt] = *(const short8*)&WlL[off];
        }
        #pragma unroll
        for (int nt = 0; nt < 2; nt++) {
          int rr = wn2 * 32 + nt * 16 + l15;
          int off = (rr >> 4) * 2048 + ((k0 >> 3) + quad) * 128 + (rr & 15) * 8;
          bh2[nt] = *(const short8*)&XhL[off];
          bl2[nt] = *(const short8*)&XlL[off];
        }
        #pragma unroll
        for (int nt = 0; nt < 2; nt++)
          #pragma unroll
          for (int mt = 0; mt < 2; mt++) {
            acc[mt][nt] = __builtin_amdgcn_mfma_f32_16x16x32_bf16(ah[mt], bh2[nt], acc[mt][nt], 0, 0, 0);
            acc[mt][nt] = __builtin_amdgcn_mfma_f32_16x16x32_bf16(ah[mt], bl2[nt], acc[mt][nt], 0, 0, 0);
            acc[mt][nt] = __builtin_amdgcn_mfma_f32_16x16x32_bf16(al[mt], bh2[nt], acc[mt][nt], 0, 0, 0);
          }
      }
    }
    // flush segment b
    #pragma unroll
    for (int mt = 0; mt < 2; mt++)
      #pragma unroll
      for (int nt = 0; nt < 2; nt++) {
        #pragma unroll
        for (int r = 0; r < 4; r++) {
          int hs = hs0 + wm * 32 + mt * 16 + quad * 4 + r;
          int dd = d0 + wn2 * 32 + nt * 16 + l15;
          atomicAdd(&G[((size_t)b * 256 + hs) * 256 + dd], acc[mt][nt][r]);
        }
        acc[mt][nt] = (f32x4){0.f, 0.f, 0.f, 0.f};
      }
  }
}

// ---------------------------------------------------------------------------
// k_attn: per (b,h): stok = G@Wfx^T + snorm*bfx (MFMA prologue, st in LDS),
// normalize, q/k/v, 32x32 attention, P = out_tok @ Wout_h -> PT bf16 hi/lo.
// ---------------------------------------------------------------------------
__global__ __launch_bounds__(256) void k_attn(
    const float* __restrict__ G, const float* __restrict__ snorm,
    const float* __restrict__ bfx,
    const short* __restrict__ Bt1h, const short* __restrict__ Bt1l,
    const float* __restrict__ Wq, const float* __restrict__ Wk,
    const float* __restrict__ Wv, const float* __restrict__ Wout,
    short* __restrict__ PTh, short* __restrict__ PTl)
{
  __shared__ float st[32][65];
  __shared__ float qs[32][65];
  __shared__ float ks[32][65];
  __shared__ float vs[32][65];
  __shared__ float at[32][33];
  __shared__ float ot[32][65];
  const int bhid = blockIdx.x;
  const int b = bhid >> 3, h = bhid & 7;
  const int tid = threadIdx.x;
  const int lane = tid & 63, l15 = lane & 15, quad = lane >> 4;
  const int wvi = tid >> 6;

  // ---- stok prologue: st[s][d] = (G[b,h*32+s,:]@WfxT[h*64+d,:] + sn*bfx)/ (sn+1e-5)
  {
    f32x4 acc2[2];
    acc2[0] = (f32x4){0.f, 0.f, 0.f, 0.f};
    acc2[1] = (f32x4){0.f, 0.f, 0.f, 0.f};
    for (int kt = 0; kt < 8; kt++) {
      size_t bsrc = (size_t)(h * 64 + wvi * 16 + l15) * 256 + kt * 32 + quad * 8;
      short8 bh = *(const short8*)&Bt1h[bsrc];
      short8 bl = *(const short8*)&Bt1l[bsrc];
      #pragma unroll
      for (int mt = 0; mt < 2; mt++) {
        const float* gp = &G[((size_t)b * 256 + h * 32 + mt * 16 + l15) * 256 + kt * 32 + quad * 8];
        float4 f1 = *(const float4*)gp;
        float4 f2 = *(const float4*)(gp + 4);
        float fv[8] = {f1.x, f1.y, f1.z, f1.w, f2.x, f2.y, f2.z, f2.w};
        short8 gh, gl2;
        #pragma unroll
        for (int j = 0; j < 8; j++) {
          short hh = f2bf(fv[j]);
          gh[j] = hh; gl2[j] = f2bf(fv[j] - bf2f(hh));
        }
        acc2[mt] = __builtin_amdgcn_mfma_f32_16x16x32_bf16(gh, bh, acc2[mt], 0, 0, 0);
        acc2[mt] = __builtin_amdgcn_mfma_f32_16x16x32_bf16(gh, bl, acc2[mt], 0, 0, 0);
        acc2[mt] = __builtin_amdgcn_mfma_f32_16x16x32_bf16(gl2, bh, acc2[mt], 0, 0, 0);
      }
    }
    int d = wvi * 16 + l15;
    float bias = bfx[h * 64 + d];
    #pragma unroll
    for (int mt = 0; mt < 2; mt++)
      #pragma unroll
      for (int r = 0; r < 4; r++) {
        int ss = mt * 16 + quad * 4 + r;
        float sn = snorm[(size_t)bhid * NS + ss];
        st[ss][d] = (acc2[mt][r] + sn * bias) / (sn + 1e-5f);
      }
  }
  __syncthreads();

  const int e = tid & 63, sgp = tid >> 6;
  for (int ii = 0; ii < 8; ii++) {
    int ss = sgp * 8 + ii;
    float aq = 0.f, ak = 0.f, av = 0.f;
    #pragma unroll 8
    for (int dd = 0; dd < 64; dd++) {
      float sv = st[ss][dd];
      aq += sv * Wq[dd * 64 + e];
      ak += sv * Wk[dd * 64 + e];
      av += sv * Wv[dd * 64 + e];
    }
    qs[ss][e] = aq; ks[ss][e] = ak; vs[ss][e] = av;
  }
  __syncthreads();

  const float scale = 0.125f;
  for (int i = tid; i < 1024; i += 256) {
    int si = i >> 5, tj = i & 31;
    float a = 0.f;
    #pragma unroll 8
    for (int ee = 0; ee < 64; ee++) a += qs[si][ee] * ks[tj][ee];
    at[si][tj] = a * scale;
  }
  __syncthreads();

  if (tid < 32) {
    float m = -1e30f;
    for (int j = 0; j < 32; j++) m = fmaxf(m, at[tid][j]);
    float sum = 0.f;
    for (int j = 0; j < 32; j++) { float ev = __expf(at[tid][j] - m); at[tid][j] = ev; sum += ev; }
    float inv = 1.f / sum;
    for (int j = 0; j < 32; j++) at[tid][j] *= inv;
  }
  __syncthreads();

  for (int ii = 0; ii < 8; ii++) {
    int ss = sgp * 8 + ii;
    float a = 0.f;
    #pragma unroll 8
    for (int tj = 0; tj < 32; tj++) a += at[ss][tj] * vs[tj][e];
    ot[ss][e] = a;
  }
  __syncthreads();

  const int s_p = tid >> 3;
  const int c0 = (tid & 7) * 32;
  float pacc[32];
  #pragma unroll
  for (int q = 0; q < 32; q++) pacc[q] = 0.f;
  for (int dd = 0; dd < 64; dd++) {
    float o = ot[s_p][dd];
    const float4* wr = (const float4*)&Wout[(size_t)(h * 64 + dd) * NDIM + c0];
    #pragma unroll
    for (int q = 0; q < 8; q++) {
      float4 v = wr[q];
      pacc[4 * q + 0] += o * v.x;
      pacc[4 * q + 1] += o * v.y;
      pacc[4 * q + 2] += o * v.z;
      pacc[4 * q + 3] += o * v.w;
    }
  }
  #pragma unroll
  for (int q = 0; q < 32; q++) {
    int c = c0 + q;
    float val = pacc[q];
    short hi = f2bf(val);
    size_t dst = ((size_t)b * NDIM + c) * 256 + h * 32 + s_p;
    PTh[dst] = hi;
    PTl[dst] = f2bf(val - bf2f(hi));
  }
}

// ---------------------------------------------------------------------------
// k_outw: out[n,c] = sum_{hs} w[n,hs] * PT[batch[n]][c][hs] + bout[c].
// (unchanged r10 version: 512 threads, 128x256 tile, BK=32.)
// ---------------------------------------------------------------------------
__global__ __launch_bounds__(512) void k_outw(
    const short* __restrict__ wh, const short* __restrict__ wl,
    const short* __restrict__ PTh, const short* __restrict__ PTl,
    const int* __restrict__ batch, const float* __restrict__ bout,
    float* __restrict__ out, int N, int ntiles)
{
  __shared__ __align__(16) short smem[24576];   // 48 KB
  short* AhL = &smem[0];
  short* AlL = &smem[4096];
  short* BhL = &smem[8192];
  short* BlL = &smem[16384];
  __shared__ int b_sh[128];

  const int lid = blockIdx.x;
  const int xcd = lid & 7;
  const int rowt = xcd + 8 * (lid >> 3);
  if (rowt >= ntiles) return;
  const int row0 = rowt * 128;
  const int tid = threadIdx.x;
  const int lane = tid & 63, l15 = lane & 15, quad = lane >> 4;
  const int wvi = tid >> 6, wm = wvi & 1, wn = wvi >> 1;
  const int srow = lane & 15, schunk = lane >> 4;
  const int cnt = min(128, N - row0);

  if (tid < 128) b_sh[tid] = (tid < cnt) ? batch[row0 + tid] : -1;
  __syncthreads();

  f32x4 acc[4][4];
  #pragma unroll
  for (int i = 0; i < 4; i++)
    #pragma unroll
    for (int j = 0; j < 4; j++) acc[i][j] = (f32x4){0.f, 0.f, 0.f, 0.f};

  int i0 = 0;
  while (i0 < cnt) {
    int b = b_sh[i0];
    int j = i0;
    while (j < cnt && b_sh[j] == b) j++;
    const bool fullseg = (i0 == 0) && (j == cnt) && (cnt == 128);

    for (int kt = 0; kt < 8; kt++) {
      if (fullseg) {
        int g = wvi;
        int gr = row0 + g * 16 + srow;
        size_t aoff = (size_t)gr * 256 + kt * 32 + schunk * 8;
        gl_lds16(wh + aoff, AhL + g * 512);
        gl_lds16(wl + aoff, AlL + g * 512);
      } else {
        int row = tid >> 2, kc8 = tid & 3;
        short8 vh = (short8){0, 0, 0, 0, 0, 0, 0, 0};
        short8 vl = (short8){0, 0, 0, 0, 0, 0, 0, 0};
        if (row >= i0 && row < j) {
          size_t src = (size_t)(row0 + row) * 256 + kt * 32 + kc8 * 8;
          vh = *(const short8*)&wh[src];
          vl = *(const short8*)&wl[src];
        }
        int dst = (row >> 4) * 512 + kc8 * 128 + (row & 15) * 8;
        *(short8*)&AhL[dst] = vh;
        *(short8*)&AlL[dst] = vl;
      }
      #pragma unroll
      for (int t = 0; t < 2; t++) {
        int g2 = wvi + t * 8;
        int br = g2 * 16 + srow;
        size_t boff = ((size_t)b * NDIM + br) * 256 + kt * 32 + schunk * 8;
        gl_lds16(PTh + boff, BhL + g2 * 512);
        gl_lds16(PTl + boff, BlL + g2 * 512);
      }
      __syncthreads();

      short8 ah[4], al[4];
      #pragma unroll
      for (int mt = 0; mt < 4; mt++) {
        int rg = wm * 4 + mt;
        ah[mt] = *(const short8*)&AhL[rg * 512 + quad * 128 + l15 * 8];
        al[mt] = *(const short8*)&AlL[rg * 512 + quad * 128 + l15 * 8];
      }
      #pragma unroll
      for (int nt = 0; nt < 4; nt++) {
        int rg = wn * 4 + nt;
        short8 bh = *(const short8*)&BhL[rg * 512 + quad * 128 + l15 * 8];
        short8 bl = *(const short8*)&BlL[rg * 512 + quad * 128 + l15 * 8];
        #pragma unroll
        for (int mt = 0; mt < 4; mt++) {
          acc[mt][nt] = __builtin_amdgcn_mfma_f32_16x16x32_bf16(ah[mt], bh, acc[mt][nt], 0, 0, 0);
          acc[mt][nt] = __builtin_amdgcn_mfma_f32_16x16x32_bf16(ah[mt], bl, acc[mt][nt], 0, 0, 0);
          acc[mt][nt] = __builtin_amdgcn_mfma_f32_16x16x32_bf16(al[mt], bh, acc[mt][nt], 0, 0, 0);
        }
      }
      __syncthreads();
    }
    i0 = j;
  }

  #pragma unroll
  for (int nt = 0; nt < 4; nt++) {
    int c = wn * 64 + nt * 16 + l15;
    float bias = bout[c];
    #pragma unroll
    for (int mt = 0; mt < 4; mt++)
      #pragma unroll
      for (int r = 0; r < 4; r++) {
        int row = row0 + wm * 64 + mt * 16 + quad * 4 + r;
        if (row < N) out[(size_t)row * NDIM + c] = acc[mt][nt][r] + bias;
      }
  }
}

// ---------------------------------------------------------------------------
extern "C" void kernel_launch(void* const* d_in, const int* in_sizes, int n_in,
                              void* d_out, int out_size, void* d_ws, size_t ws_size,
                              hipStream_t stream) {
  const float* x      = (const float*)d_in[0];
  const int*   batch  = (const int*)d_in[1];
  const float* Wfx    = (const float*)d_in[2];
  const float* bfx    = (const float*)d_in[3];
  const float* Wx     = (const float*)d_in[4];
  const float* bx     = (const float*)d_in[5];
  const float* Wsl    = (const float*)d_in[6];
  const float* bsl    = (const float*)d_in[7];
  const float* gtemp  = (const float*)d_in[8];
  const float* Wq     = (const float*)d_in[9];
  const float* Wk     = (const float*)d_in[10];
  const float* Wv     = (const float*)d_in[11];
  const float* Wout   = (const float*)d_in[12];
  const float* bout   = (const float*)d_in[13];
  float* out = (float*)d_out;

  const int N = in_sizes[0] / NDIM;   // 30000

  float* G     = (float*)d_ws;                     // [8][256][256] fp32 = 2MB
  float* snorm = G + 524288;                       // 2048
  float* bcomb = snorm + 2048;                     // 256
  int*   seg   = (int*)(bcomb + 256);              // 16
  short* Bt1h  = (short*)(seg + 16);               // 196608
  short* Bt1l  = Bt1h + 196608;
  short* XTh   = Bt1l + 196608;                    // [256][NP]
  short* XTl   = XTh + (size_t)256 * NP;
  short* whb   = XTl + (size_t)256 * NP;           // [NP][256] row-major w
  short* wlb   = whb + (size_t)NP * 256;
  short* wTh   = wlb + (size_t)NP * 256;           // [256][NP]
  short* wTl   = wTh + (size_t)256 * NP;
  short* PTh   = wTl + (size_t)256 * NP;           // 524288
  short* PTl   = PTh + 524288;

  hipMemsetAsync(G, 0, (size_t)(524288 + 2048) * sizeof(float), stream);
  hipMemsetAsync(seg, 0x7f, 16 * sizeof(int), stream);

  k_pre<<<887 + 1888, 256, 0, stream>>>(
      x, Wfx, Wx, bx, Wsl, bsl, Bt1h, Bt1l, bcomb, batch, seg, XTh, XTl, N);

  const int ntiles = (N + 127) / 128;              // 235
  const int qmax = (ntiles + 7) / 8;               // 30
  k_w<<<8 * qmax * 4, 256, 0, stream>>>(x, Bt1h, Bt1l, bcomb, gtemp, batch,
                                        whb, wlb, wTh, wTl, snorm, N, ntiles);

  dim3 gG(16, (N + 511) / 512);
  k_G<<<gG, 256, 0, stream>>>(wTh, wTl, XTh, XTl, seg, G, N);

  k_attn<<<NB * NH, 256, 0, stream>>>(G, snorm, bfx, Bt1h, Bt1l,
                                      Wq, Wk, Wv, Wout, PTh, PTl);

  k_outw<<<8 * qmax, 512, 0, stream>>>(whb, wlb, PTh, PTl, batch, bout, out, N, ntiles);
}